// Round 2
// baseline (2618.155 us; speedup 1.0000x reference)
//
#include <hip/hip_runtime.h>
#include <stdint.h>

#define BATCH 32
#define HWD 224
#define PATCH 16
#define HP 14
#define NP (BATCH * HP * HP)   // 6272 patches
#define DIM 768
#define EMB 768
#define K0 512
#define K1 2048
#define K2 8192

#define MT 64    // patches per block tile
#define NT 128   // centers per chunk
#define DT 32    // d-dim chunk

typedef unsigned long long ull;

__device__ __forceinline__ unsigned int fkey(float f) {
    unsigned int u = __float_as_uint(f);
    return (u & 0x80000000u) ? ~u : (u | 0x80000000u);  // monotone fp32 -> u32
}

// ---------------- patchify: data[b,3,224,224] -> x[p=6272][d=768] ----------------
__global__ void patchify_kernel(const float* __restrict__ data, float* __restrict__ x) {
    int gid = blockIdx.x * 256 + threadIdx.x;
    int d = gid % DIM;
    int p = gid / DIM;
    int b = p / 196; int t = p % 196; int i = t / 14, j = t % 14;
    int ch = d >> 8; int r = d & 255; int py = r >> 4; int px = r & 15;
    x[gid] = data[((b * 3 + ch) * HWD + i * PATCH + py) * HWD + j * PATCH + px];
}

// ---------------- center row norms ----------------
__global__ void norms_kernel(const float* __restrict__ c, float* __restrict__ nrm) {
    int k = blockIdx.x;
    const float* row = c + (size_t)k * DIM;
    float s = 0.f;
    for (int d = threadIdx.x; d < DIM; d += 64) { float v = row[d]; s += v * v; }
    #pragma unroll
    for (int off = 32; off; off >>= 1) s += __shfl_down(s, off, 64);
    if (threadIdx.x == 0) nrm[k] = s;
}

__global__ void init_slots_kernel(ull* __restrict__ slots) {
    int i = blockIdx.x * 256 + threadIdx.x;
    if (i < NP) slots[i] = 0xFFFFFFFFFFFFFFFFull;
}

// ---------------- classify: argmin_k ||v_p - c_k||^2 (as ||c||^2 - 2 v.c) ----------------
// Block tile 64m x 128n, per-thread 8m x 4n. DT=32 -> LDS 24KB -> 4+ blocks/CU.
// Compute reads: cs lane-sequential float4 (conflict-free), xs 2-address broadcast.
__global__ __launch_bounds__(256, 4) void classify_kernel(
    const float* __restrict__ v, const float* __restrict__ cent,
    const float* __restrict__ cnorm, int kCount,
    ull* __restrict__ slots)
{
    __shared__ __align__(16) float cs[DT][NT];  // 16 KB
    __shared__ __align__(16) float xs[MT][DT];  // 8 KB
    const int pbase = blockIdx.x * MT;
    const int kBase = blockIdx.y * kCount;
    const int tid = threadIdx.x;
    const int tm = tid >> 5;   // 0..7  -> m rows tm*8 .. tm*8+7
    const int tn = tid & 31;   // 0..31 -> n cols tn*4 .. tn*4+3

    float best[8];
    int bidx[8];
    #pragma unroll
    for (int mi = 0; mi < 8; ++mi) { best[mi] = 3.4e38f; bidx[mi] = 0; }

    // staging decode (hoisted)
    const int xm0 = tid >> 3;            // 0..31
    const int xd0 = (tid & 7) * 4;       // 0..28
    const int crow = tid >> 1;           // 0..127
    const int cd0 = (tid & 1) * 16;      // 0 or 16

    for (int nc = 0; nc < kCount; nc += NT) {
        float acc[8][4];
        #pragma unroll
        for (int mi = 0; mi < 8; ++mi)
            #pragma unroll
            for (int ni = 0; ni < 4; ++ni) acc[mi][ni] = 0.f;

        for (int dc = 0; dc < DIM; dc += DT) {
            // x tile 64x32 row-major: flat lane-sequential float4 stores
            *(float4*)(&xs[xm0][xd0]) =
                *(const float4*)(v + (size_t)(pbase + xm0) * DIM + dc + xd0);
            *(float4*)(&xs[xm0 + 32][xd0]) =
                *(const float4*)(v + (size_t)(pbase + xm0 + 32) * DIM + dc + xd0);
            // c tile transposed cs[d][n]: thread stages half a center row (16 d's)
            {
                const float* src = cent + (size_t)(kBase + nc + crow) * DIM + dc + cd0;
                #pragma unroll
                for (int q = 0; q < 4; ++q) {
                    float4 a = *(const float4*)(src + q * 4);
                    cs[cd0 + q * 4 + 0][crow] = a.x;
                    cs[cd0 + q * 4 + 1][crow] = a.y;
                    cs[cd0 + q * 4 + 2][crow] = a.z;
                    cs[cd0 + q * 4 + 3][crow] = a.w;
                }
            }
            __syncthreads();
            #pragma unroll
            for (int d = 0; d < DT; d += 4) {
                float4 xr[8];
                #pragma unroll
                for (int mi = 0; mi < 8; ++mi)
                    xr[mi] = *(const float4*)(&xs[tm * 8 + mi][d]);
                #pragma unroll
                for (int dd = 0; dd < 4; ++dd) {
                    const float4 cv = *(const float4*)(&cs[d + dd][tn * 4]);
                    const float cn4[4] = {cv.x, cv.y, cv.z, cv.w};
                    #pragma unroll
                    for (int mi = 0; mi < 8; ++mi) {
                        const float xm = ((const float*)&xr[mi])[dd];
                        #pragma unroll
                        for (int ni = 0; ni < 4; ++ni)
                            acc[mi][ni] = fmaf(xm, cn4[ni], acc[mi][ni]);
                    }
                }
            }
            __syncthreads();
        }
        // scores + running argmin (ascending k within thread; ties -> lowest k)
        #pragma unroll
        for (int ni = 0; ni < 4; ++ni) {
            int k = kBase + nc + tn * 4 + ni;
            float nor = cnorm[k];
            #pragma unroll
            for (int mi = 0; mi < 8; ++mi) {
                float s = fmaf(-2.f, acc[mi][ni], nor);
                if (s < best[mi]) { best[mi] = s; bidx[mi] = k; }
            }
        }
    }
    // reduce across the 32 tn threads (half-wave), then atomicMin across blocks
    #pragma unroll
    for (int mi = 0; mi < 8; ++mi) {
        ull pk = ((ull)fkey(best[mi]) << 32) | (unsigned int)bidx[mi];
        #pragma unroll
        for (int off = 16; off; off >>= 1) {
            ull o = __shfl_xor(pk, off, 32);
            if (o < pk) pk = o;
        }
        if (tn == 0) atomicMin(&slots[pbase + tm * 8 + mi], pk);
    }
}

// ---------------- update: v -= c[cls];  store cls ----------------
__global__ void update_kernel(float* __restrict__ v, const float* __restrict__ cent,
                              const ull* __restrict__ slots, int* __restrict__ cls) {
    int gid = blockIdx.x * 256 + threadIdx.x;
    int p = gid / DIM, d = gid % DIM;
    int idx = (int)(slots[p] & 0xFFFFFFFFull);
    v[gid] -= cent[(size_t)idx * DIM + d];
    if (d == 0) cls[p] = idx;
}

// ---------------- finalize: embed / img_sum / diff_out with layout transposes ----------------
__global__ void finalize_kernel(const float* __restrict__ vdiff,
    const int* __restrict__ cls0, const int* __restrict__ cls1, const int* __restrict__ cls2,
    const float* __restrict__ c0, const float* __restrict__ c1, const float* __restrict__ c2,
    const float* __restrict__ e0, const float* __restrict__ e1, const float* __restrict__ e2,
    float* __restrict__ out)
{
    int p = blockIdx.x;
    int b = p / 196, t = p % 196, i = t / 14, j = t % 14;
    int i0 = cls0[p], i1 = cls1[p], i2 = cls2[p];
    float* out_embed = out;
    float* out_img   = out + (size_t)NP * DIM;
    float* out_diff  = out + 2 * (size_t)NP * DIM;
    for (int d = threadIdx.x; d < DIM; d += 256) {
        float ev = e0[(size_t)i0 * EMB + d] + e1[(size_t)i1 * EMB + d] + e2[(size_t)i2 * EMB + d];
        out_embed[((b * EMB + d) * HP + i) * HP + j] = ev;

        float iv = c0[(size_t)i0 * DIM + d] + c1[(size_t)i1 * DIM + d] + c2[(size_t)i2 * DIM + d];
        int ch = d >> 8, r = d & 255, py = r >> 4, px = r & 15;
        out_img[((b * 3 + ch) * HWD + i * PATCH + py) * HWD + j * PATCH + px] = iv;

        out_diff[((b * DIM + d) * HP + i) * HP + j] = vdiff[(size_t)p * DIM + d];
    }
}

extern "C" void kernel_launch(void* const* d_in, const int* in_sizes, int n_in,
                              void* d_out, int out_size, void* d_ws, size_t ws_size,
                              hipStream_t stream) {
    const float* data = (const float*)d_in[0];
    const float* c0 = (const float*)d_in[1];
    const float* c1 = (const float*)d_in[2];
    const float* c2 = (const float*)d_in[3];
    const float* e0 = (const float*)d_in[4];
    const float* e1 = (const float*)d_in[5];
    const float* e2 = (const float*)d_in[6];
    float* out = (float*)d_out;

    char* w = (char*)d_ws;
    float* xbuf = (float*)w;            w += (size_t)NP * DIM * 4;   // 19.27 MB
    ull* slots = (ull*)w;               w += (size_t)NP * 8;
    int* cls0 = (int*)w;                w += (size_t)NP * 4;
    int* cls1 = (int*)w;                w += (size_t)NP * 4;
    int* cls2 = (int*)w;                w += (size_t)NP * 4;
    float* nrm0 = (float*)w;            w += (size_t)K0 * 4;
    float* nrm1 = (float*)w;            w += (size_t)K1 * 4;
    float* nrm2 = (float*)w;            w += (size_t)K2 * 4;

    const int ELEM_BLOCKS = (NP * DIM) / 256;   // 18816
    const int PB = NP / MT;                     // 98 patch tiles

    patchify_kernel<<<ELEM_BLOCKS, 256, 0, stream>>>(data, xbuf);
    norms_kernel<<<K0, 64, 0, stream>>>(c0, nrm0);
    norms_kernel<<<K1, 64, 0, stream>>>(c1, nrm1);
    norms_kernel<<<K2, 64, 0, stream>>>(c2, nrm2);

    // level 0: K=512, split 4 -> kCount=128 (1 NT chunk), grid 392
    init_slots_kernel<<<(NP + 255) / 256, 256, 0, stream>>>(slots);
    classify_kernel<<<dim3(PB, 4), 256, 0, stream>>>(xbuf, c0, nrm0, K0 / 4, slots);
    update_kernel<<<ELEM_BLOCKS, 256, 0, stream>>>(xbuf, c0, slots, cls0);

    // level 1: K=2048, split 8 -> kCount=256, grid 784
    init_slots_kernel<<<(NP + 255) / 256, 256, 0, stream>>>(slots);
    classify_kernel<<<dim3(PB, 8), 256, 0, stream>>>(xbuf, c1, nrm1, K1 / 8, slots);
    update_kernel<<<ELEM_BLOCKS, 256, 0, stream>>>(xbuf, c1, slots, cls1);

    // level 2: K=8192, split 16 -> kCount=512, grid 1568
    init_slots_kernel<<<(NP + 255) / 256, 256, 0, stream>>>(slots);
    classify_kernel<<<dim3(PB, 16), 256, 0, stream>>>(xbuf, c2, nrm2, K2 / 16, slots);
    update_kernel<<<ELEM_BLOCKS, 256, 0, stream>>>(xbuf, c2, slots, cls2);

    finalize_kernel<<<NP, 256, 0, stream>>>(xbuf, cls0, cls1, cls2,
                                            c0, c1, c2, e0, e1, e2, out);
}

// Round 4
// 657.245 us; speedup vs baseline: 3.9835x; 3.9835x over previous
//
#include <hip/hip_runtime.h>
#include <stdint.h>

#define BATCH 32
#define HWD 224
#define HP 14
#define NP (BATCH * HP * HP)   // 6272 patches = 49 * 128
#define DIM 768
#define K0 512
#define K1 2048
#define K2 8192

typedef unsigned long long ull;
typedef unsigned int uint;
typedef __attribute__((ext_vector_type(8))) short bf16x8;
typedef __attribute__((ext_vector_type(4))) float f32x4;

__device__ __forceinline__ uint fkey(float f) {
    uint u = __float_as_uint(f);
    return (u & 0x80000000u) ? ~u : (u | 0x80000000u);  // monotone fp32 -> u32
}
__device__ __forceinline__ short f2bf(float f) {       // round-to-nearest-even bf16
    uint u = __float_as_uint(f);
    uint r = (u + 0x7fffu + ((u >> 16) & 1u)) >> 16;
    return (short)r;
}
__device__ __forceinline__ float bf2f(short h) {
    return __uint_as_float(((uint)(unsigned short)h) << 16);
}
__device__ __forceinline__ ull umin64(ull a, ull b) { return a < b ? a : b; }
__device__ __forceinline__ ull umax64(ull a, ull b) { return a > b ? a : b; }

// ---------------- patchify + bf16 hi/lo split (residual kept as hi/lo pair) ----------------
__global__ void patchify_split_kernel(const float* __restrict__ data,
                                      short* __restrict__ xh, short* __restrict__ xl) {
    int gid = blockIdx.x * 256 + threadIdx.x;   // covers NP*DIM exactly
    int d = gid % DIM;
    int p = gid / DIM;
    int b = p / 196; int t = p % 196; int i = t / 14, j = t % 14;
    int ch = d >> 8; int r = d & 255; int py = r >> 4; int px = r & 15;
    float v = data[((b * 3 + ch) * HWD + i * 16 + py) * HWD + j * 16 + px];
    short h = f2bf(v);
    xh[gid] = h;
    xl[gid] = f2bf(v - bf2f(h));
}

// ---------------- center prep: bf16 hi/lo + row norms ----------------
__global__ void cprep_kernel(const float* __restrict__ c, short* __restrict__ ch,
                             short* __restrict__ cl, float* __restrict__ nrm) {
    int lane = threadIdx.x & 63;
    int row = blockIdx.x * 4 + (threadIdx.x >> 6);
    const float* src = c + (size_t)row * DIM;
    float s = 0.f;
    #pragma unroll
    for (int i = 0; i < 12; ++i) {
        int d = lane + i * 64;
        float v = src[d];
        short h = f2bf(v);
        ch[(size_t)row * DIM + d] = h;
        cl[(size_t)row * DIM + d] = f2bf(v - bf2f(h));
        s += v * v;
    }
    #pragma unroll
    for (int off = 32; off; off >>= 1) s += __shfl_xor(s, off, 64);
    if (lane == 0) nrm[row] = s;
}

// ---------------- MFMA classify (verified 16x16x32 layouts) ----------------
// Block 256 thr = 4 waves (wm = w&1 selects m-half, wn = w>>1 selects n-half).
// Block tile: M=128, N=2*NHT*16. Wave tile: 64m x NHT*16 n of 16x16 tiles.
// LDS is in FRAGMENT ORDER: slot(16B) = region + tile*64 + lane holds
// row (tile*16 + (lane&15)), elements [dc + (lane>>4)*8, +8).
// A-frag: A[m=lane&15][k=(lane>>4)*8+j]; B-frag from B^T rows (same shape);
// C/D: col=lane&15, row=(lane>>4)*4+reg.  [all measured: learn_hip m89-m97]
template<int NHT>
__global__ __launch_bounds__(256, 2) void classify16(
    const short* __restrict__ xh, const short* __restrict__ xl,
    const short* __restrict__ chv, const short* __restrict__ clv,
    const float* __restrict__ nrm,
    ull* __restrict__ partB, ull* __restrict__ partS2)
{
    constexpr int NB = 2 * NHT * 16;        // block N (256 or 128)
    constexpr int CH0 = 1024;               // ch slot base
    constexpr int CL0 = 1024 + 128 * NHT;   // cl slot base
    constexpr int NJ = (16 + 4 * NHT) / 4;  // staging instrs per wave (12 or 8)
    __shared__ __align__(16) short lds[(1024 + 256 * NHT) * 8];

    const int tid = threadIdx.x;
    const int lane = tid & 63;
    const int w = tid >> 6;
    const int wm = w & 1, wn = w >> 1;
    const int pbase = blockIdx.x * 128;
    const int n0 = blockIdx.y * NB;

    // staging descriptors: group g covers slots [region + t*64, +64)
    const short* gp[NJ];
    int ls[NJ];
    #pragma unroll
    for (int j = 0; j < NJ; ++j) {
        int g = j * 4 + w;
        const short* base; int rb, sb, t;
        if (g < 8)               { base = xh;  rb = pbase; sb = 0;    t = g; }
        else if (g < 16)         { base = xl;  rb = pbase; sb = 512;  t = g - 8; }
        else if (g < 16 + 2*NHT) { base = chv; rb = n0;    sb = CH0;  t = g - 16; }
        else                     { base = clv; rb = n0;    sb = CL0;  t = g - 16 - 2*NHT; }
        gp[j] = base + (size_t)(rb + t * 16 + (lane & 15)) * DIM + ((lane >> 4) * 8);
        ls[j] = sb + t * 64;
    }

    f32x4 acc[4][NHT];
    #pragma unroll
    for (int i = 0; i < 4; ++i)
        #pragma unroll
        for (int u = 0; u < NHT; ++u) acc[i][u] = (f32x4){0.f, 0.f, 0.f, 0.f};

    const bf16x8* L = (const bf16x8*)lds;

    for (int dc = 0; dc < DIM; dc += 32) {
        #pragma unroll
        for (int j = 0; j < NJ; ++j) {
            __builtin_amdgcn_global_load_lds(
                (const __attribute__((address_space(1))) void*)(gp[j] + dc),
                (__attribute__((address_space(3))) void*)(lds + (size_t)ls[j] * 8),
                16, 0, 0);
        }
        __syncthreads();
        bf16x8 fxh[4], fxl[4];
        #pragma unroll
        for (int i = 0; i < 4; ++i) {
            fxh[i] = L[(wm * 4 + i) * 64 + lane];
            fxl[i] = L[512 + (wm * 4 + i) * 64 + lane];
        }
        #pragma unroll
        for (int u = 0; u < NHT; ++u) {
            bf16x8 fch = L[CH0 + (wn * NHT + u) * 64 + lane];
            bf16x8 fcl = L[CL0 + (wn * NHT + u) * 64 + lane];
            #pragma unroll
            for (int i = 0; i < 4; ++i) {
                acc[i][u] = __builtin_amdgcn_mfma_f32_16x16x32_bf16(fxh[i], fch, acc[i][u], 0, 0, 0);
                acc[i][u] = __builtin_amdgcn_mfma_f32_16x16x32_bf16(fxh[i], fcl, acc[i][u], 0, 0, 0);
                acc[i][u] = __builtin_amdgcn_mfma_f32_16x16x32_bf16(fxl[i], fch, acc[i][u], 0, 0, 0);
            }
        }
        __syncthreads();
    }

    // epilogue: per-row top-2 over this block's wave-half (NB/2 centers)
    float nor[NHT]; uint ncol[NHT];
    #pragma unroll
    for (int u = 0; u < NHT; ++u) {
        ncol[u] = (uint)(n0 + (wn * NHT + u) * 16 + (lane & 15));
        nor[u] = nrm[ncol[u]];
    }
    #pragma unroll
    for (int i = 0; i < 4; ++i) {
        #pragma unroll
        for (int reg = 0; reg < 4; ++reg) {
            ull b = ~0ull, s2 = ~0ull;
            #pragma unroll
            for (int u = 0; u < NHT; ++u) {
                float s = fmaf(-2.f, acc[i][u][reg], nor[u]);
                ull pk = ((ull)fkey(s) << 32) | ncol[u];
                ull nb = umin64(b, pk);
                s2 = umin64(s2, umax64(b, pk));
                b = nb;
            }
            #pragma unroll
            for (int off = 1; off <= 8; off <<= 1) {   // reduce across lane&15
                ull ob = __shfl_xor(b, off, 64);
                ull os2 = __shfl_xor(s2, off, 64);
                ull nb = umin64(b, ob);
                s2 = umin64(umin64(s2, os2), umax64(b, ob));
                b = nb;
            }
            if ((lane & 15) == 0) {
                int row = pbase + (wm * 4 + i) * 16 + (lane >> 4) * 4 + reg;
                size_t o = (size_t)row * 64 + blockIdx.y * 2 + wn;
                partB[o] = b;
                partS2[o] = s2;
            }
        }
    }
}

// ---------------- merge partials + exact fp32 rescue + residual update ----------------
__global__ void merge_rescue_update(
    short* __restrict__ xh, short* __restrict__ xl,
    const float* __restrict__ cent, const float* __restrict__ nrm,
    const ull* __restrict__ partB, const ull* __restrict__ partS2,
    int nsplit, int* __restrict__ cls)
{
    int lane = threadIdx.x & 63;
    int p = blockIdx.x * 4 + (threadIdx.x >> 6);
    ull b = ~0ull, s2 = ~0ull;
    if (lane < nsplit) {
        b = partB[(size_t)p * 64 + lane];
        s2 = partS2[(size_t)p * 64 + lane];
    }
    #pragma unroll
    for (int off = 32; off; off >>= 1) {
        ull ob = __shfl_xor(b, off, 64);
        ull os2 = __shfl_xor(s2, off, 64);
        ull nb = umin64(b, ob);
        s2 = umin64(umin64(s2, os2), umax64(b, ob));
        b = nb;
    }
    int i1 = (int)(b & 0xFFFFFFFFull);
    int i2 = (int)(s2 & 0xFFFFFFFFull);
    const float* c1r = cent + (size_t)i1 * DIM;
    const float* c2r = cent + (size_t)i2 * DIM;
    float d1 = 0.f, d2 = 0.f;
    #pragma unroll
    for (int i = 0; i < 12; ++i) {
        int d = lane + i * 64;
        float xv = bf2f(xh[(size_t)p * DIM + d]) + bf2f(xl[(size_t)p * DIM + d]);
        d1 = fmaf(xv, c1r[d], d1);
        d2 = fmaf(xv, c2r[d], d2);
    }
    #pragma unroll
    for (int off = 32; off; off >>= 1) { d1 += __shfl_xor(d1, off, 64); d2 += __shfl_xor(d2, off, 64); }
    float sc1 = fmaf(-2.f, d1, nrm[i1]);
    float sc2 = fmaf(-2.f, d2, nrm[i2]);
    int cw = (sc2 < sc1 || (sc2 == sc1 && i2 < i1)) ? i2 : i1;
    if (lane == 0) cls[p] = cw;
    const float* cwr = cent + (size_t)cw * DIM;
    #pragma unroll
    for (int i = 0; i < 12; ++i) {
        int d = lane + i * 64;
        float nx = bf2f(xh[(size_t)p * DIM + d]) + bf2f(xl[(size_t)p * DIM + d]) - cwr[d];
        short h = f2bf(nx);
        xh[(size_t)p * DIM + d] = h;
        xl[(size_t)p * DIM + d] = f2bf(nx - bf2f(h));
    }
}

// ---------------- embed + diff outputs (LDS transpose, coalesced writes) ----------------
__global__ void embdiff_kernel(const short* __restrict__ xh, const short* __restrict__ xl,
    const int* __restrict__ cls0, const int* __restrict__ cls1, const int* __restrict__ cls2,
    const float* __restrict__ e0, const float* __restrict__ e1, const float* __restrict__ e2,
    float* __restrict__ out)
{
    __shared__ float s[196][65];
    int b = blockIdx.x / 12;
    int dc = (blockIdx.x % 12) * 64;
    int tid = threadIdx.x;
    int dl = tid & 63;
    // embed
    for (int it = 0; it < 49; ++it) {
        int pl = it * 4 + (tid >> 6);
        int p = b * 196 + pl;
        int d = dc + dl;
        s[pl][dl] = e0[(size_t)cls0[p] * DIM + d] + e1[(size_t)cls1[p] * DIM + d]
                  + e2[(size_t)cls2[p] * DIM + d];
    }
    __syncthreads();
    if (tid < 196) {
        for (int d = 0; d < 64; ++d)
            out[((size_t)b * DIM + dc + d) * 196 + tid] = s[tid][d];
    }
    __syncthreads();
    // diff (residual = xh + xl)
    for (int it = 0; it < 49; ++it) {
        int pl = it * 4 + (tid >> 6);
        size_t o = (size_t)(b * 196 + pl) * DIM + dc + dl;
        s[pl][dl] = bf2f(xh[o]) + bf2f(xl[o]);
    }
    __syncthreads();
    if (tid < 196) {
        float* od = out + 2 * (size_t)NP * DIM;
        for (int d = 0; d < 64; ++d)
            od[((size_t)b * DIM + dc + d) * 196 + tid] = s[tid][d];
    }
}

// ---------------- img_sum output ----------------
__global__ void img_kernel(
    const int* __restrict__ cls0, const int* __restrict__ cls1, const int* __restrict__ cls2,
    const float* __restrict__ c0, const float* __restrict__ c1, const float* __restrict__ c2,
    float* __restrict__ out)
{
    __shared__ float s[14][256];
    int bi = blockIdx.x;
    int b = bi / 42; int rem = bi % 42; int ch = rem / 14; int i = rem % 14;
    int tid = threadIdx.x;
    for (int j = 0; j < 14; ++j) {
        int p = b * 196 + i * 14 + j;
        int d = ch * 256 + tid;
        s[j][tid] = c0[(size_t)cls0[p] * DIM + d] + c1[(size_t)cls1[p] * DIM + d]
                  + c2[(size_t)cls2[p] * DIM + d];
    }
    __syncthreads();
    float* oi = out + (size_t)NP * DIM;
    if (tid < 224) {
        int j = tid >> 4, px = tid & 15;
        for (int py = 0; py < 16; ++py)
            oi[(((size_t)b * 3 + ch) * HWD + i * 16 + py) * HWD + tid] = s[j][py * 16 + px];
    }
}

extern "C" void kernel_launch(void* const* d_in, const int* in_sizes, int n_in,
                              void* d_out, int out_size, void* d_ws, size_t ws_size,
                              hipStream_t stream) {
    const float* data = (const float*)d_in[0];
    const float* c0 = (const float*)d_in[1];
    const float* c1 = (const float*)d_in[2];
    const float* c2 = (const float*)d_in[3];
    const float* e0 = (const float*)d_in[4];
    const float* e1 = (const float*)d_in[5];
    const float* e2 = (const float*)d_in[6];
    float* out = (float*)d_out;

    char* w = (char*)d_ws;
    short* xh = (short*)w;    w += (size_t)NP * DIM * 2;      // 9.63 MB
    short* xl = (short*)w;    w += (size_t)NP * DIM * 2;      // 9.63 MB
    short* chB = (short*)w;   w += (size_t)K2 * DIM * 2;      // 12.58 MB
    short* clB = (short*)w;   w += (size_t)K2 * DIM * 2;      // 12.58 MB
    float* nrm = (float*)w;   w += (size_t)K2 * 4;            // 32 KB
    ull* partB = (ull*)w;     w += (size_t)NP * 64 * 8;       // 3.21 MB
    ull* partS2 = (ull*)w;    w += (size_t)NP * 64 * 8;       // 3.21 MB
    int* cls0 = (int*)w;      w += (size_t)NP * 4;
    int* cls1 = (int*)w;      w += (size_t)NP * 4;
    int* cls2 = (int*)w;      w += (size_t)NP * 4;
    // total ~48.6 MiB < out_size bytes (57.8 MB)

    patchify_split_kernel<<<(NP * DIM) / 256, 256, 0, stream>>>(data, xh, xl);

    // level 0: K=512, N/block=128 (NHT=4), grid (49,4) -> 8 partials
    cprep_kernel<<<K0 / 4, 256, 0, stream>>>(c0, chB, clB, nrm);
    classify16<4><<<dim3(NP / 128, 4), 256, 0, stream>>>(xh, xl, chB, clB, nrm, partB, partS2);
    merge_rescue_update<<<NP / 4, 256, 0, stream>>>(xh, xl, c0, nrm, partB, partS2, 8, cls0);

    // level 1: K=2048, N/block=256 (NHT=8), grid (49,8) -> 16 partials
    cprep_kernel<<<K1 / 4, 256, 0, stream>>>(c1, chB, clB, nrm);
    classify16<8><<<dim3(NP / 128, 8), 256, 0, stream>>>(xh, xl, chB, clB, nrm, partB, partS2);
    merge_rescue_update<<<NP / 4, 256, 0, stream>>>(xh, xl, c1, nrm, partB, partS2, 16, cls1);

    // level 2: K=8192, N/block=256 (NHT=8), grid (49,32) -> 64 partials
    cprep_kernel<<<K2 / 4, 256, 0, stream>>>(c2, chB, clB, nrm);
    classify16<8><<<dim3(NP / 128, 32), 256, 0, stream>>>(xh, xl, chB, clB, nrm, partB, partS2);
    merge_rescue_update<<<NP / 4, 256, 0, stream>>>(xh, xl, c2, nrm, partB, partS2, 64, cls2);

    embdiff_kernel<<<BATCH * 12, 256, 0, stream>>>(xh, xl, cls0, cls1, cls2, e0, e1, e2, out);
    img_kernel<<<BATCH * 3 * 14, 256, 0, stream>>>(cls0, cls1, cls2, c0, c1, c2, out);
}

// Round 5
// 592.618 us; speedup vs baseline: 4.4179x; 1.1091x over previous
//
#include <hip/hip_runtime.h>
#include <stdint.h>

#define BATCH 32
#define HWD 224
#define HP 14
#define NP (BATCH * HP * HP)   // 6272 patches = 49 * 128
#define DIM 768
#define K0 512
#define K1 2048
#define K2 8192

typedef unsigned long long ull;
typedef unsigned int uint;
typedef __attribute__((ext_vector_type(8))) short bf16x8;
typedef __attribute__((ext_vector_type(4))) float f32x4;

__device__ __forceinline__ uint fkey(float f) {
    uint u = __float_as_uint(f);
    return (u & 0x80000000u) ? ~u : (u | 0x80000000u);  // monotone fp32 -> u32
}
__device__ __forceinline__ short f2bf(float f) {       // round-to-nearest-even bf16
    uint u = __float_as_uint(f);
    uint r = (u + 0x7fffu + ((u >> 16) & 1u)) >> 16;
    return (short)r;
}
__device__ __forceinline__ float bf2f(short h) {
    return __uint_as_float(((uint)(unsigned short)h) << 16);
}
__device__ __forceinline__ ull umin64(ull a, ull b) { return a < b ? a : b; }
__device__ __forceinline__ ull umax64(ull a, ull b) { return a > b ? a : b; }

// ---------------- patchify + bf16 hi/lo split (residual kept as hi/lo pair) ----------------
__global__ void patchify_split_kernel(const float* __restrict__ data,
                                      short* __restrict__ xh, short* __restrict__ xl) {
    int gid = blockIdx.x * 256 + threadIdx.x;   // covers NP*DIM exactly
    int d = gid % DIM;
    int p = gid / DIM;
    int b = p / 196; int t = p % 196; int i = t / 14, j = t % 14;
    int ch = d >> 8; int r = d & 255; int py = r >> 4; int px = r & 15;
    float v = data[((b * 3 + ch) * HWD + i * 16 + py) * HWD + j * 16 + px];
    short h = f2bf(v);
    xh[gid] = h;
    xl[gid] = f2bf(v - bf2f(h));
}

// ---------------- center prep: bf16 hi/lo + row norms ----------------
__global__ void cprep_kernel(const float* __restrict__ c, short* __restrict__ ch,
                             short* __restrict__ cl, float* __restrict__ nrm) {
    int lane = threadIdx.x & 63;
    int row = blockIdx.x * 4 + (threadIdx.x >> 6);
    const float* src = c + (size_t)row * DIM;
    float s = 0.f;
    #pragma unroll
    for (int i = 0; i < 12; ++i) {
        int d = lane + i * 64;
        float v = src[d];
        short h = f2bf(v);
        ch[(size_t)row * DIM + d] = h;
        cl[(size_t)row * DIM + d] = f2bf(v - bf2f(h));
        s += v * v;
    }
    #pragma unroll
    for (int off = 32; off; off >>= 1) s += __shfl_xor(s, off, 64);
    if (lane == 0) nrm[row] = s;
}

// ---------------- MFMA classify (verified 16x16x32 layouts) ----------------
// 2-term split: x.c ~= xh.ch + xh.cl  (error = xl.c, sigma ~0.02 on the dot).
// Block 256 thr = 4 waves (wm = w&1 selects m-half, wn = w>>1 selects n-half).
// Block tile: M=128, N=2*NHT*16. Wave tile: 64m x NHT*16 n of 16x16 tiles.
// LDS in FRAGMENT ORDER: slot(16B) = region + tile*64 + lane holds
// row (tile*16 + (lane&15)), elements [dc + (lane>>4)*8, +8).
// A-frag: A[m=lane&15][k=(lane>>4)*8+j]; B-frag from B^T rows (same shape);
// C/D: col=lane&15, row=(lane>>4)*4+reg.  [all measured: learn_hip m89-m97]
template<int NHT>
__global__ __launch_bounds__(256, 2) void classify16(
    const short* __restrict__ xh,
    const short* __restrict__ chv, const short* __restrict__ clv,
    const float* __restrict__ nrm,
    ull* __restrict__ partB, ull* __restrict__ partS2)
{
    constexpr int NB = 2 * NHT * 16;        // block N (256 or 128)
    constexpr int CH0 = 512;                // ch slot base
    constexpr int CL0 = 512 + 128 * NHT;    // cl slot base
    constexpr int NJ = (8 + 4 * NHT) / 4;   // staging instrs per wave (10 or 6)
    __shared__ __align__(16) short lds[(512 + 256 * NHT) * 8];   // 40 KB / 24 KB

    const int tid = threadIdx.x;
    const int lane = tid & 63;
    const int w = tid >> 6;
    const int wm = w & 1, wn = w >> 1;
    const int pbase = blockIdx.x * 128;
    const int n0 = blockIdx.y * NB;

    // staging descriptors: group g covers slots [region + t*64, +64)
    const short* gp[NJ];
    int ls[NJ];
    #pragma unroll
    for (int j = 0; j < NJ; ++j) {
        int g = j * 4 + w;
        const short* base; int rb, sb, t;
        if (g < 8)              { base = xh;  rb = pbase; sb = 0;    t = g; }
        else if (g < 8 + 2*NHT) { base = chv; rb = n0;    sb = CH0;  t = g - 8; }
        else                    { base = clv; rb = n0;    sb = CL0;  t = g - 8 - 2*NHT; }
        gp[j] = base + (size_t)(rb + t * 16 + (lane & 15)) * DIM + ((lane >> 4) * 8);
        ls[j] = sb + t * 64;
    }

    f32x4 acc[4][NHT];
    #pragma unroll
    for (int i = 0; i < 4; ++i)
        #pragma unroll
        for (int u = 0; u < NHT; ++u) acc[i][u] = (f32x4){0.f, 0.f, 0.f, 0.f};

    const bf16x8* L = (const bf16x8*)lds;

    for (int dc = 0; dc < DIM; dc += 32) {
        #pragma unroll
        for (int j = 0; j < NJ; ++j) {
            __builtin_amdgcn_global_load_lds(
                (const __attribute__((address_space(1))) void*)(gp[j] + dc),
                (__attribute__((address_space(3))) void*)(lds + (size_t)ls[j] * 8),
                16, 0, 0);
        }
        __syncthreads();
        bf16x8 fxh[4];
        #pragma unroll
        for (int i = 0; i < 4; ++i)
            fxh[i] = L[(wm * 4 + i) * 64 + lane];
        #pragma unroll
        for (int u = 0; u < NHT; ++u) {
            bf16x8 fch = L[CH0 + (wn * NHT + u) * 64 + lane];
            bf16x8 fcl = L[CL0 + (wn * NHT + u) * 64 + lane];
            #pragma unroll
            for (int i = 0; i < 4; ++i) {
                acc[i][u] = __builtin_amdgcn_mfma_f32_16x16x32_bf16(fxh[i], fch, acc[i][u], 0, 0, 0);
                acc[i][u] = __builtin_amdgcn_mfma_f32_16x16x32_bf16(fxh[i], fcl, acc[i][u], 0, 0, 0);
            }
        }
        __syncthreads();
    }

    // epilogue: per-row top-2 over this block's wave-half (NB/2 centers)
    float nor[NHT]; uint ncol[NHT];
    #pragma unroll
    for (int u = 0; u < NHT; ++u) {
        ncol[u] = (uint)(n0 + (wn * NHT + u) * 16 + (lane & 15));
        nor[u] = nrm[ncol[u]];
    }
    #pragma unroll
    for (int i = 0; i < 4; ++i) {
        #pragma unroll
        for (int reg = 0; reg < 4; ++reg) {
            ull b = ~0ull, s2 = ~0ull;
            #pragma unroll
            for (int u = 0; u < NHT; ++u) {
                float s = fmaf(-2.f, acc[i][u][reg], nor[u]);
                ull pk = ((ull)fkey(s) << 32) | ncol[u];
                ull nb = umin64(b, pk);
                s2 = umin64(s2, umax64(b, pk));
                b = nb;
            }
            #pragma unroll
            for (int off = 1; off <= 8; off <<= 1) {   // reduce across lane&15
                ull ob = __shfl_xor(b, off, 64);
                ull os2 = __shfl_xor(s2, off, 64);
                ull nb = umin64(b, ob);
                s2 = umin64(umin64(s2, os2), umax64(b, ob));
                b = nb;
            }
            if ((lane & 15) == 0) {
                int row = pbase + (wm * 4 + i) * 16 + (lane >> 4) * 4 + reg;
                size_t o = (size_t)row * 64 + blockIdx.y * 2 + wn;
                partB[o] = b;
                partS2[o] = s2;
            }
        }
    }
}

// ---------------- merge partials + exact fp32 top-4 rescue + residual update ----------------
__global__ void merge_rescue_update(
    short* __restrict__ xh, short* __restrict__ xl,
    const float* __restrict__ cent, const float* __restrict__ nrm,
    const ull* __restrict__ partB, const ull* __restrict__ partS2,
    int nsplit, int* __restrict__ cls)
{
    int lane = threadIdx.x & 63;
    int p = blockIdx.x * 4 + (threadIdx.x >> 6);
    ull a = ~0ull, c = ~0ull;
    if (lane < nsplit) {
        a = partB[(size_t)p * 64 + lane];
        c = partS2[(size_t)p * 64 + lane];
    }
    // extract top-4 candidates (packed keys unique: idx appears once)
    int idx[4];
    #pragma unroll
    for (int r = 0; r < 4; ++r) {
        ull m = a;
        #pragma unroll
        for (int off = 32; off; off >>= 1) m = umin64(m, __shfl_xor(m, off, 64));
        idx[r] = (int)(m & 0xFFFFFFFFull);
        if (a == m) { a = c; c = ~0ull; }   // pop from owning lane
    }
    // x reconstructed once into registers
    float xv[12];
    #pragma unroll
    for (int i = 0; i < 12; ++i) {
        int d = lane + i * 64;
        xv[i] = bf2f(xh[(size_t)p * DIM + d]) + bf2f(xl[(size_t)p * DIM + d]);
    }
    float dot[4] = {0.f, 0.f, 0.f, 0.f};
    #pragma unroll
    for (int r = 0; r < 4; ++r) {
        const float* cr = cent + (size_t)idx[r] * DIM;
        #pragma unroll
        for (int i = 0; i < 12; ++i) dot[r] = fmaf(xv[i], cr[lane + i * 64], dot[r]);
    }
    #pragma unroll
    for (int r = 0; r < 4; ++r)
        #pragma unroll
        for (int off = 32; off; off >>= 1) dot[r] += __shfl_xor(dot[r], off, 64);
    ull best = ~0ull;
    #pragma unroll
    for (int r = 0; r < 4; ++r) {
        float sc = fmaf(-2.f, dot[r], nrm[idx[r]]);
        best = umin64(best, ((ull)fkey(sc) << 32) | (uint)idx[r]);  // ties -> lower idx
    }
    int cw = (int)(best & 0xFFFFFFFFull);
    if (lane == 0) cls[p] = cw;
    const float* cwr = cent + (size_t)cw * DIM;
    #pragma unroll
    for (int i = 0; i < 12; ++i) {
        int d = lane + i * 64;
        float nx = xv[i] - cwr[d];
        short h = f2bf(nx);
        xh[(size_t)p * DIM + d] = h;
        xl[(size_t)p * DIM + d] = f2bf(nx - bf2f(h));
    }
}

// ---------------- embed + diff outputs (LDS transpose, coalesced writes) ----------------
__global__ void embdiff_kernel(const short* __restrict__ xh, const short* __restrict__ xl,
    const int* __restrict__ cls0, const int* __restrict__ cls1, const int* __restrict__ cls2,
    const float* __restrict__ e0, const float* __restrict__ e1, const float* __restrict__ e2,
    float* __restrict__ out)
{
    __shared__ float s[196][65];
    int b = blockIdx.x / 12;
    int dc = (blockIdx.x % 12) * 64;
    int tid = threadIdx.x;
    int dl = tid & 63;
    // embed
    for (int it = 0; it < 49; ++it) {
        int pl = it * 4 + (tid >> 6);
        int p = b * 196 + pl;
        int d = dc + dl;
        s[pl][dl] = e0[(size_t)cls0[p] * DIM + d] + e1[(size_t)cls1[p] * DIM + d]
                  + e2[(size_t)cls2[p] * DIM + d];
    }
    __syncthreads();
    if (tid < 196) {
        for (int d = 0; d < 64; ++d)
            out[((size_t)b * DIM + dc + d) * 196 + tid] = s[tid][d];
    }
    __syncthreads();
    // diff (residual = xh + xl)
    for (int it = 0; it < 49; ++it) {
        int pl = it * 4 + (tid >> 6);
        size_t o = (size_t)(b * 196 + pl) * DIM + dc + dl;
        s[pl][dl] = bf2f(xh[o]) + bf2f(xl[o]);
    }
    __syncthreads();
    if (tid < 196) {
        float* od = out + 2 * (size_t)NP * DIM;
        for (int d = 0; d < 64; ++d)
            od[((size_t)b * DIM + dc + d) * 196 + tid] = s[tid][d];
    }
}

// ---------------- img_sum output ----------------
__global__ void img_kernel(
    const int* __restrict__ cls0, const int* __restrict__ cls1, const int* __restrict__ cls2,
    const float* __restrict__ c0, const float* __restrict__ c1, const float* __restrict__ c2,
    float* __restrict__ out)
{
    __shared__ float s[14][256];
    int bi = blockIdx.x;
    int b = bi / 42; int rem = bi % 42; int ch = rem / 14; int i = rem % 14;
    int tid = threadIdx.x;
    for (int j = 0; j < 14; ++j) {
        int p = b * 196 + i * 14 + j;
        int d = ch * 256 + tid;
        s[j][tid] = c0[(size_t)cls0[p] * DIM + d] + c1[(size_t)cls1[p] * DIM + d]
                  + c2[(size_t)cls2[p] * DIM + d];
    }
    __syncthreads();
    float* oi = out + (size_t)NP * DIM;
    if (tid < 224) {
        int j = tid >> 4, px = tid & 15;
        for (int py = 0; py < 16; ++py)
            oi[(((size_t)b * 3 + ch) * HWD + i * 16 + py) * HWD + tid] = s[j][py * 16 + px];
    }
}

extern "C" void kernel_launch(void* const* d_in, const int* in_sizes, int n_in,
                              void* d_out, int out_size, void* d_ws, size_t ws_size,
                              hipStream_t stream) {
    const float* data = (const float*)d_in[0];
    const float* c0 = (const float*)d_in[1];
    const float* c1 = (const float*)d_in[2];
    const float* c2 = (const float*)d_in[3];
    const float* e0 = (const float*)d_in[4];
    const float* e1 = (const float*)d_in[5];
    const float* e2 = (const float*)d_in[6];
    float* out = (float*)d_out;

    char* w = (char*)d_ws;
    short* xh = (short*)w;    w += (size_t)NP * DIM * 2;      // 9.63 MB
    short* xl = (short*)w;    w += (size_t)NP * DIM * 2;      // 9.63 MB
    short* chB = (short*)w;   w += (size_t)K2 * DIM * 2;      // 12.58 MB
    short* clB = (short*)w;   w += (size_t)K2 * DIM * 2;      // 12.58 MB
    float* nrm = (float*)w;   w += (size_t)K2 * 4;            // 32 KB
    ull* partB = (ull*)w;     w += (size_t)NP * 64 * 8;       // 3.21 MB
    ull* partS2 = (ull*)w;    w += (size_t)NP * 64 * 8;       // 3.21 MB
    int* cls0 = (int*)w;      w += (size_t)NP * 4;
    int* cls1 = (int*)w;      w += (size_t)NP * 4;
    int* cls2 = (int*)w;      w += (size_t)NP * 4;
    // total ~48.6 MiB

    patchify_split_kernel<<<(NP * DIM) / 256, 256, 0, stream>>>(data, xh, xl);

    // level 0: K=512, N/block=128 (NHT=4), grid (49,4) -> 8 partials
    cprep_kernel<<<K0 / 4, 256, 0, stream>>>(c0, chB, clB, nrm);
    classify16<4><<<dim3(NP / 128, 4), 256, 0, stream>>>(xh, chB, clB, nrm, partB, partS2);
    merge_rescue_update<<<NP / 4, 256, 0, stream>>>(xh, xl, c0, nrm, partB, partS2, 8, cls0);

    // level 1: K=2048, N/block=256 (NHT=8), grid (49,8) -> 16 partials
    cprep_kernel<<<K1 / 4, 256, 0, stream>>>(c1, chB, clB, nrm);
    classify16<8><<<dim3(NP / 128, 8), 256, 0, stream>>>(xh, chB, clB, nrm, partB, partS2);
    merge_rescue_update<<<NP / 4, 256, 0, stream>>>(xh, xl, c1, nrm, partB, partS2, 16, cls1);

    // level 2: K=8192, N/block=256 (NHT=8), grid (49,32) -> 64 partials
    cprep_kernel<<<K2 / 4, 256, 0, stream>>>(c2, chB, clB, nrm);
    classify16<8><<<dim3(NP / 128, 32), 256, 0, stream>>>(xh, chB, clB, nrm, partB, partS2);
    merge_rescue_update<<<NP / 4, 256, 0, stream>>>(xh, xl, c2, nrm, partB, partS2, 64, cls2);

    embdiff_kernel<<<BATCH * 12, 256, 0, stream>>>(xh, xl, cls0, cls1, cls2, e0, e1, e2, out);
    img_kernel<<<BATCH * 3 * 14, 256, 0, stream>>>(cls0, cls1, cls2, c0, c1, c2, out);
}